// Round 11
// baseline (15615.649 us; speedup 1.0000x reference)
//
#include <hip/hip_runtime.h>
#include <stdint.h>
#include <stddef.h>

// ---------------------------------------------------------------------------
// LFADS forward on MI355X — round 18.
// R17 diagnosis: __launch_bounds__(1024) let the compiler target 8 waves/SIMD
// (VGPR cap 64) for occupancy our 1-block/CU grids never use -> the 18-uint4
// register caches SPILLED (encoder WRITE_SIZE 128->173MB = scratch stores;
// gen regressed to ~9.7ms). Fix: __launch_bounds__(1024, 4) = 4 waves/EU =
// exactly our 16-wave block -> 128-VGPR budget -> caches stay in registers.
// Everything else identical to R17 (single-variable experiment).
// ---------------------------------------------------------------------------

#define B_    128
#define T_    1000
#define DIN_  64
#define E_    256
#define F_    64
#define H1_   80
#define DOUT_ 64
#define CLIPV 5.0f
#define LVMIN_ (-9.210340371976182f)
#define TC_   128
#define NCHUNK_ 8

typedef _Float16 f16;
typedef _Float16 f16x2 __attribute__((ext_vector_type(2)));

__device__ __forceinline__ float sigm_(float x) { return 1.0f/(1.0f + expf(-x)); }

__device__ __forceinline__ float dot2_(f16x2 a, f16x2 b, float c) {
  asm("v_dot2_f32_f16 %0, %1, %2, %0" : "+v"(c) : "v"(a), "v"(b));
  return c;
}
#define P0_(Wv) __builtin_bit_cast(f16x2, (Wv).x)
#define P1_(Wv) __builtin_bit_cast(f16x2, (Wv).y)
#define P2_(Wv) __builtin_bit_cast(f16x2, (Wv).z)
#define P3_(Wv) __builtin_bit_cast(f16x2, (Wv).w)
#define DOT4(Av, Wv, Hv) \
  Av = dot2_(P0_(Wv), P0_(Hv), Av); Av = dot2_(P1_(Wv), P1_(Hv), Av); \
  Av = dot2_(P2_(Wv), P2_(Hv), Av); Av = dot2_(P3_(Wv), P3_(Hv), Av);

// ------------------------- weight prep --------------------------------------
// Encoder weights per chain fp16: ih [k8<8][m<3][j<256][i<8], then
// hh [k8<32][m<3][j<256][i<8]  (49152 + 196608 = 245760 halfs)

struct PEncArgs { const float* wih[4]; const float* whh[4]; f16* dst; };

__global__ __launch_bounds__(256) void k_prep_enc(PEncArgs a) {
  const int chain = blockIdx.y;
  const int idx = blockIdx.x*256 + threadIdx.x;     // < 245760
  float v;
  if (idx < 49152) {
    const int i = idx & 7, j = (idx >> 3) & 255;
    const int r = idx >> 11;                        // < 24
    const int m = r % 3, k8 = r / 3;                // k8 < 8
    v = a.wih[chain][((size_t)(m*E_ + j))*DIN_ + k8*8 + i];
  } else {
    const int t = idx - 49152;
    const int i = t & 7, j = (t >> 3) & 255;
    const int r = t >> 11;                          // < 96
    const int m = r % 3, k8 = r / 3;                // k8 < 32
    v = a.whh[chain][((size_t)(m*E_ + j))*E_ + k8*8 + i];
  }
  a.dst[(size_t)chain*245760 + idx] = (f16)v;
}

// Generator recurrent weights fp16: [k8<32][m<6][j<256][i<8]
// m 0..2 = con_whh r/z/n (dot c); m 3..5 = gen_whh r/z/n (dot g)
__global__ __launch_bounds__(256) void k_prep_gen(const float* __restrict__ conwhh,
                                                  const float* __restrict__ genwhh,
                                                  f16* __restrict__ wg6) {
  const int idx = blockIdx.x*256 + threadIdx.x;     // < 393216
  const int i = idx & 7, j = (idx >> 3) & 255;
  const int r = idx >> 11;                          // < 192
  const int m = r % 6, k8 = r / 6;                  // k8 < 32
  const int k = k8*8 + i;
  const float v = (m < 3) ? conwhh[(size_t)(m*E_ + j)*E_ + k]
                          : genwhh[(size_t)((m-3)*E_ + j)*E_ + k];
  wg6[idx] = (f16)v;
}

// W3 = con_wih[:, 512:576] fp16: [k8<8][m<3][j<256][i<8] (dot f)
__global__ __launch_bounds__(256) void k_prep_w3(const float* __restrict__ conwih,
                                                 f16* __restrict__ w3) {
  const int idx = blockIdx.x*256 + threadIdx.x;     // < 49152
  const int i = idx & 7, j = (idx >> 3) & 255;
  const int r = idx >> 11;                          // < 24
  const int m = r % 3, k8 = r / 3;                  // k8 < 8
  w3[idx] = (f16)conwih[(size_t)(m*E_ + j)*576 + 512 + k8*8 + i];
}

// W2 = con_wih[:, 0:512] fp16: [k8<64][m<3][j<256][i<8]
__global__ __launch_bounds__(256) void k_prep_w2(const float* __restrict__ conwih,
                                                 f16* __restrict__ w2) {
  const int idx = blockIdx.x*256 + threadIdx.x;     // < 393216
  const int i = idx & 7, j = (idx >> 3) & 255;
  const int r = idx >> 11;                          // < 192
  const int m = r % 3, k8 = r / 3;                  // k8 < 64
  w2[idx] = (f16)conwih[(size_t)(m*E_ + j)*576 + k8*8 + i];
}

// Per-feature fused biases: [j][8] f32 (fac_b flows through f)
__global__ void k_prep_bias(const float* __restrict__ conbih,
                            const float* __restrict__ conbhh,
                            const float* __restrict__ genbih,
                            const float* __restrict__ genbhh,
                            float* __restrict__ bias8) {
  const int j = threadIdx.x;
  float* o = bias8 + j*8;
  o[0] = conbih[j]      + conbhh[j];      // con r
  o[1] = conbih[E_+j]   + conbhh[E_+j];   // con z
  o[2] = conbih[2*E_+j];                  // con n (input)
  o[3] = conbhh[2*E_+j];                  // con n (hidden)
  o[4] = genbih[j]      + genbhh[j];      // gen r
  o[5] = genbih[E_+j]   + genbhh[E_+j];   // gen z
  o[6] = genbih[2*E_+j];                  // gen n (input)
  o[7] = genbhh[2*E_+j];                  // gen n (hidden)
}

// ------------------------- encoder ------------------------------------------
// 256 blocks = 4 chains x 64 pairs (2 batches); 1024 threads = (j, kq<4)
// kq0: ih (8 k8) + hh k8 0-1; kq1: hh 2-11; kq2: 12-21; kq3: 22-31
// Register cache: 6 k8-triples (18 uint4) per thread; VGPR budget 128 via
// launch_bounds(1024, 4) — grid is exactly 1 block/CU so no occupancy cost.

struct EncArgs {
  const float* x;                       // [B][T][64]
  const float* bih[4]; const float* bhh[4];
  const f16* wenc;                      // [4][245760]
  f16* efS; f16* ebS;                   // [B][T][256]
  float* hgF; float* hgB;               // [128][256]
};

__global__ __launch_bounds__(1024, 4) void k_encoder(EncArgs a) {
  __shared__ __align__(16) f16 shh[2][256];
  __shared__ __align__(16) f16 sxh[2][64];
  __shared__ float shf[2][256];
  __shared__ float sred[3][6][256];           // kq 1..3 partials [q*3+g][j]
  const int chain = blockIdx.x >> 6;
  const int pair  = blockIdx.x & 63;
  const int b0 = pair*2;
  const int j  = threadIdx.x & 255;
  const int kq = threadIdx.x >> 8;
  const bool bwd = (chain >= 2);
  const f16* Wih = a.wenc + (size_t)chain*245760;
  const f16* Whh = Wih + 49152;
  f16* st = (chain==1) ? a.efS : (chain==3 ? a.ebS : nullptr);
  float* hgout = (chain==0) ? a.hgF : (chain==2 ? a.hgB : nullptr);

  float br=0,bz=0,bni=0,bnh=0;
  if (kq == 0) {
    br  = a.bih[chain][j]      + a.bhh[chain][j];
    bz  = a.bih[chain][E_+j]   + a.bhh[chain][E_+j];
    bni = a.bih[chain][2*E_+j];
    bnh = a.bhh[chain][2*E_+j];
  }
  if (threadIdx.x < 512) {
    shf[threadIdx.x>>8][threadIdx.x&255] = 0.f;
    shh[threadIdx.x>>8][threadIdx.x&255] = (f16)0.f;
  }
  float xv = 0.f;
  if (kq == 0 && j < 128) {
    const int q = j >> 6, k = j & 63;
    const int tt0 = bwd ? (T_-1) : 0;
    xv = a.x[((size_t)(b0+q)*T_ + tt0)*DIN_ + k];
  }
  const f16* wpi = Wih + (size_t)j*8;
  const f16* wph = Whh + (size_t)j*8;
  const int ks1 = 2 + (kq-1)*10;              // kq>=1 stream base

  // ---- loop-invariant register weight cache: 18 uint4 (6 triples) ----
  uint4 RC[18];
  if (kq == 0) {
    #pragma unroll
    for (int i = 0; i < 18; ++i)
      RC[i] = *(const uint4*)(wpi + (size_t)i*2048);        // ih k8 0..5
  } else {
    #pragma unroll
    for (int i = 0; i < 18; ++i)
      RC[i] = *(const uint4*)(wph + (size_t)(ks1*3 + i)*2048); // hh ks1..ks1+5
  }

  for (int t = 0; t < T_; ++t) {
    const int tt = bwd ? (T_-1-t) : t;
    if (kq == 0 && j < 128) sxh[j>>6][j&63] = (f16)xv;
    __syncthreads();                          // BAR1: x_t + h_{t-1} published
    if (kq == 0 && j < 128 && t+1 < T_) {
      const int q = j >> 6, k = j & 63;
      const int tn = bwd ? (T_-2-t) : (t+1);
      xv = a.x[((size_t)(b0+q)*T_ + tn)*DIN_ + k];
    }
    float ar[2]={0,0}, az[2]={0,0}, ani[2]={0,0}, anh[2]={0,0};
    if (kq == 0) {
      // cached ih k8 0..5
      #pragma unroll
      for (int k8 = 0; k8 < 6; ++k8) {
        #pragma unroll
        for (int q = 0; q < 2; ++q) {
          const uint4 xq = *(const uint4*)(&sxh[q][k8*8]);
          DOT4(ar[q], RC[k8*3+0], xq); DOT4(az[q], RC[k8*3+1], xq);
          DOT4(ani[q], RC[k8*3+2], xq);
        }
      }
      // streamed ih k8 6..7
      #pragma unroll
      for (int k8 = 6; k8 < 8; ++k8) {
        const uint4 c0 = *(const uint4*)(wpi + (size_t)(k8*3+0)*2048);
        const uint4 c1 = *(const uint4*)(wpi + (size_t)(k8*3+1)*2048);
        const uint4 c2 = *(const uint4*)(wpi + (size_t)(k8*3+2)*2048);
        #pragma unroll
        for (int q = 0; q < 2; ++q) {
          const uint4 xq = *(const uint4*)(&sxh[q][k8*8]);
          DOT4(ar[q], c0, xq); DOT4(az[q], c1, xq); DOT4(ani[q], c2, xq);
        }
      }
      // streamed hh k8 0..1
      #pragma unroll
      for (int k8 = 0; k8 < 2; ++k8) {
        const uint4 c0 = *(const uint4*)(wph + (size_t)(k8*3+0)*2048);
        const uint4 c1 = *(const uint4*)(wph + (size_t)(k8*3+1)*2048);
        const uint4 c2 = *(const uint4*)(wph + (size_t)(k8*3+2)*2048);
        #pragma unroll
        for (int q = 0; q < 2; ++q) {
          const uint4 hq = *(const uint4*)(&shh[q][k8*8]);
          DOT4(ar[q], c0, hq); DOT4(az[q], c1, hq); DOT4(anh[q], c2, hq);
        }
      }
    } else {
      // cached hh ks1..ks1+5
      #pragma unroll
      for (int i = 0; i < 6; ++i) {
        const int k8 = ks1 + i;
        #pragma unroll
        for (int q = 0; q < 2; ++q) {
          const uint4 hq = *(const uint4*)(&shh[q][k8*8]);
          DOT4(ar[q], RC[i*3+0], hq); DOT4(az[q], RC[i*3+1], hq);
          DOT4(anh[q], RC[i*3+2], hq);
        }
      }
      // streamed hh ks1+6..ks1+9
      #pragma unroll 2
      for (int kk = 6; kk < 10; ++kk) {
        const int k8 = ks1 + kk;
        const uint4 c0 = *(const uint4*)(wph + (size_t)(k8*3+0)*2048);
        const uint4 c1 = *(const uint4*)(wph + (size_t)(k8*3+1)*2048);
        const uint4 c2 = *(const uint4*)(wph + (size_t)(k8*3+2)*2048);
        #pragma unroll
        for (int q = 0; q < 2; ++q) {
          const uint4 hq = *(const uint4*)(&shh[q][k8*8]);
          DOT4(ar[q], c0, hq); DOT4(az[q], c1, hq); DOT4(anh[q], c2, hq);
        }
      }
      #pragma unroll
      for (int q = 0; q < 2; ++q) {
        sred[kq-1][q*3+0][j] = ar[q];
        sred[kq-1][q*3+1][j] = az[q];
        sred[kq-1][q*3+2][j] = anh[q];
      }
    }
    __syncthreads();                          // BAR2
    if (kq == 0) {
      #pragma unroll
      for (int q = 0; q < 2; ++q) {
        const float arq  = ar[q]  + sred[0][q*3+0][j] + sred[1][q*3+0][j]
                         + sred[2][q*3+0][j] + br;
        const float azq  = az[q]  + sred[0][q*3+1][j] + sred[1][q*3+1][j]
                         + sred[2][q*3+1][j] + bz;
        const float anhq = anh[q] + sred[0][q*3+2][j] + sred[1][q*3+2][j]
                         + sred[2][q*3+2][j] + bnh;
        const float r = sigm_(arq);
        const float z = sigm_(azq);
        const float n = tanhf(ani[q] + bni + r*anhq);
        const float hn = fminf((1.f - z)*n + z*shf[q][j], CLIPV);
        shf[q][j] = hn;
        shh[q][j] = (f16)hn;
        if (st) st[((size_t)(b0+q)*T_ + tt)*E_ + j] = (f16)hn;
        if (hgout && t == T_-1) hgout[(size_t)(b0+q)*E_ + j] = hn;
      }
    }
  }
}

// ------------------------- g0 sample ----------------------------------------

__global__ __launch_bounds__(256) void k_g0(const float* __restrict__ hgF,
                                            const float* __restrict__ hgB,
                                            const float* __restrict__ g0mw,
                                            const float* __restrict__ g0mb,
                                            const float* __restrict__ g0vw,
                                            const float* __restrict__ g0vb,
                                            const float* __restrict__ epsg0,
                                            float* __restrict__ S) {
  __shared__ __align__(16) float sf[E_], sb[E_];
  const int b = blockIdx.x, k = threadIdx.x;
  sf[k] = hgF[(size_t)b*E_ + k];
  sb[k] = hgB[(size_t)b*E_ + k];
  __syncthreads();
  const float* mr = g0mw + (size_t)k*512;
  const float* vr = g0vw + (size_t)k*512;
  float dm = 0.f, dv = 0.f;
  for (int i = 0; i < E_; i += 4) {
    const float4 m4 = *(const float4*)(mr + i);
    const float4 v4 = *(const float4*)(vr + i);
    const float4 h4 = *(const float4*)&sf[i];
    dm += m4.x*h4.x + m4.y*h4.y + m4.z*h4.z + m4.w*h4.w;
    dv += v4.x*h4.x + v4.y*h4.y + v4.z*h4.z + v4.w*h4.w;
  }
  for (int i = 0; i < E_; i += 4) {
    const float4 m4 = *(const float4*)(mr + 256 + i);
    const float4 v4 = *(const float4*)(vr + 256 + i);
    const float4 h4 = *(const float4*)&sb[i];
    dm += m4.x*h4.x + m4.y*h4.y + m4.z*h4.z + m4.w*h4.w;
    dv += v4.x*h4.x + v4.y*h4.y + v4.z*h4.z + v4.w*h4.w;
  }
  const float lv = fmaxf(dv + g0vb[k], LVMIN_);
  const float g  = epsg0[(size_t)b*E_ + k]*expf(0.5f*lv) + dm + g0mb[k];
  S[(size_t)b*512 + k]       = g;
  S[(size_t)b*512 + 256 + k] = 0.f;
}

// ------------------------- ge chunk GEMM ------------------------------------

struct GeArgs { const f16* efS; const f16* ebS; const f16* w2; f16* ge; int t0; };

__global__ __launch_bounds__(256) void k_ge(GeArgs a) {
  __shared__ __align__(16) f16 A[8][512];
  const int tile = blockIdx.x, b = blockIdx.y;
  const int tl0 = tile*8;
  const int j = threadIdx.x;
  for (int r = 0; r < 16; ++r) {
    const int idx = r*256 + j;
    const int tt = idx >> 9, k = idx & 511;
    const int t = a.t0 + tl0 + tt;
    f16 v = (f16)0.f;
    if (t < T_)
      v = (k < 256) ? a.efS[((size_t)b*T_ + t)*E_ + k]
                    : a.ebS[((size_t)b*T_ + t)*E_ + (k-256)];
    A[tt][k] = v;
  }
  __syncthreads();
  float acc[3][8];
  #pragma unroll
  for (int m = 0; m < 3; ++m)
    #pragma unroll
    for (int tt = 0; tt < 8; ++tt) acc[m][tt] = 0.f;
  const f16* wb = a.w2 + (size_t)j*8;
  #pragma unroll 2
  for (int k8 = 0; k8 < 64; ++k8) {
    uint4 av[8];
    #pragma unroll
    for (int tt = 0; tt < 8; ++tt) av[tt] = *(const uint4*)&A[tt][k8*8];
    #pragma unroll
    for (int m = 0; m < 3; ++m) {
      const uint4 wm = *(const uint4*)(wb + (size_t)(k8*3+m)*2048);
      DOT4(acc[m][0], wm, av[0]); DOT4(acc[m][1], wm, av[1]);
      DOT4(acc[m][2], wm, av[2]); DOT4(acc[m][3], wm, av[3]);
      DOT4(acc[m][4], wm, av[4]); DOT4(acc[m][5], wm, av[5]);
      DOT4(acc[m][6], wm, av[6]); DOT4(acc[m][7], wm, av[7]);
    }
  }
  #pragma unroll
  for (int m = 0; m < 3; ++m)
    #pragma unroll
    for (int tt = 0; tt < 8; ++tt)
      a.ge[((size_t)b*TC_ + tl0+tt)*768 + m*E_ + j] = (f16)acc[m][tt];
}

// ------------------------- generator ----------------------------------------
// 128 blocks = 1 batch each; 1024 threads = (j, kq<4)
// kq0: wg6 k8 0-8; kq1: 9-17; kq2: 18-26; kq3: 27-31 + W3 (f part)
// Register cache: 3 k8-hextuples (18 uint4); VGPR budget 128 via
// launch_bounds(1024, 4).

struct GenArgs {
  const f16* wg6;          // [32][6][256][8]
  const f16* w3;           // [8][3][256][8]
  const f16* ge;           // [B][TC_][768]
  const float* bias8;      // [256][8]
  const float* genwih;     // [768][2]
  const float* umw; const float* umb; const float* uvw; const float* uvb;
  const float* epsu;       // [B][T][2]
  const float* facw; const float* facb;
  float* S;                // [B][512]
  char* fout;              // f32 f[64] at byte (b*T+t)*512 (aliases efS)
  int t0, tcnt;
};

__global__ __launch_bounds__(1024, 4) void k_gen(GenArgs a) {
  __shared__ __align__(16) f16 sgh[256], sch[256], sfh[64];
  __shared__ float sgf[256], scf[256];
  __shared__ float sred[3][7][256];            // kq1..3: ar,az,ani,anh,gr,gz,gh
  __shared__ float s_ured[4][4];
  __shared__ __align__(16) f16 sfac2[16384];   // [k2<128][d<64][2]
  __shared__ float s_fred[16][64];
  const int b = blockIdx.x;
  const int tid = threadIdx.x;
  const int j  = tid & 255;
  const int kq = tid >> 8;
  const int lane = tid & 63;
  const int wv = (tid >> 6) & 3;

  for (int idx = tid; idx < 16384; idx += 1024) {
    const int k = idx >> 6, d = idx & 63;
    sfac2[(size_t)(k>>1)*128 + d*2 + (k&1)] = (f16)a.facw[(size_t)d*E_ + k];
  }
  if (kq == 0) {
    const float g0v = a.S[(size_t)b*512 + j];
    const float c0v = a.S[(size_t)b*512 + 256 + j];
    sgf[j] = g0v; sgh[j] = (f16)g0v;
    scf[j] = c0v; sch[j] = (f16)c0v;
  }
  float b_rc=0,b_zc=0,b_nc=0,b_nhc=0,b_rg=0,b_zg=0,b_ng=0,b_nhg=0;
  float gur0=0,gur1=0,guz0=0,guz1=0,gun0=0,gun1=0;
  float uwm0=0,uwm1=0,uwv0=0,uwv1=0,umb0=0,umb1=0,uvb0=0,uvb1=0;
  float facb_l = 0.f;
  if (kq == 0) {
    const float* B8 = a.bias8 + j*8;
    b_rc=B8[0]; b_zc=B8[1]; b_nc=B8[2]; b_nhc=B8[3];
    b_rg=B8[4]; b_zg=B8[5]; b_ng=B8[6]; b_nhg=B8[7];
    gur0 = a.genwih[j*2];          gur1 = a.genwih[j*2+1];
    guz0 = a.genwih[(E_+j)*2];     guz1 = a.genwih[(E_+j)*2+1];
    gun0 = a.genwih[(2*E_+j)*2];   gun1 = a.genwih[(2*E_+j)*2+1];
    uwm0 = a.umw[j]; uwm1 = a.umw[E_+j];
    uwv0 = a.uvw[j]; uwv1 = a.uvw[E_+j];
    umb0 = a.umb[0]; umb1 = a.umb[1];
    uvb0 = a.uvb[0]; uvb1 = a.uvb[1];
  }
  if (tid < 64) facb_l = a.facb[tid];
  const f16* wb6 = a.wg6 + (size_t)j*8;
  const f16* wb3 = a.w3  + (size_t)j*8;
  const int ks = kq*9;                      // 0,9,18,27
  const int ke = (kq==3) ? 32 : ks+9;

  // ---- loop-invariant register cache: 3 k8-hextuples = 18 uint4 ----
  uint4 GC[18];
  #pragma unroll
  for (int i = 0; i < 3; ++i)
    #pragma unroll
    for (int m = 0; m < 6; ++m)
      GC[i*6+m] = *(const uint4*)(wb6 + ((size_t)(ks+i)*6 + m)*2048);
  __syncthreads();

  // prologue: f_prev = fac_w @ g_prev + fac_b
  {
    const int d = tid & 63, grp = tid >> 6;
    float fp = 0.f;
    #pragma unroll
    for (int k2 = grp*8; k2 < grp*8+8; ++k2)
      fp = dot2_(*(const f16x2*)(sfac2 + (size_t)(k2*64 + d)*2),
                 *(const f16x2*)(&sgh[k2*2]), fp);
    s_fred[grp][d] = fp;
  }
  __syncthreads();
  if (tid < 64) {
    float fv = facb_l;
    #pragma unroll
    for (int g = 0; g < 16; ++g) fv += s_fred[g][tid];
    sfh[tid] = (f16)fv;
  }
  __syncthreads();

  for (int tl = 0; tl < a.tcnt; ++tl) {
    const int t = a.t0 + tl;
    float ge_r=0, ge_z=0, ge_n=0;
    float2 ev = {0,0};
    if (kq == 0) {
      const f16* gp = a.ge + ((size_t)b*TC_ + tl)*768;
      ge_r = (float)gp[j]; ge_z = (float)gp[E_+j]; ge_n = (float)gp[2*E_+j];
      ev = *(const float2*)(a.epsu + ((size_t)b*T_ + t)*2);
    }
    float ar=0, az=0, ani=0, anh=0, gr=0, gz=0, gh=0;
    {
      // cached k8 = ks .. ks+2
      #pragma unroll
      for (int i = 0; i < 3; ++i) {
        const int k8 = ks + i;
        const uint4 gv = *(const uint4*)&sgh[k8*8];
        const uint4 cv = *(const uint4*)&sch[k8*8];
        DOT4(ar,  GC[i*6+0], cv);
        DOT4(az,  GC[i*6+1], cv);
        DOT4(anh, GC[i*6+2], cv);
        DOT4(gr,  GC[i*6+3], gv);
        DOT4(gz,  GC[i*6+4], gv);
        DOT4(gh,  GC[i*6+5], gv);
      }
      // streamed k8 = ks+3 .. ke-1
      #pragma unroll 2
      for (int k8 = ks+3; k8 < ke; ++k8) {
        const f16* wk = wb6 + (size_t)k8*6*2048;
        const uint4 gv = *(const uint4*)&sgh[k8*8];
        const uint4 cv = *(const uint4*)&sch[k8*8];
        uint4 ww;
        ww = *(const uint4*)(wk + 0*2048); DOT4(ar, ww, cv);
        ww = *(const uint4*)(wk + 1*2048); DOT4(az, ww, cv);
        ww = *(const uint4*)(wk + 2*2048); DOT4(anh, ww, cv);
        ww = *(const uint4*)(wk + 3*2048); DOT4(gr, ww, gv);
        ww = *(const uint4*)(wk + 4*2048); DOT4(gz, ww, gv);
        ww = *(const uint4*)(wk + 5*2048); DOT4(gh, ww, gv);
      }
      if (kq == 3) {
        #pragma unroll 2
        for (int k8 = 0; k8 < 8; ++k8) {
          const f16* wk = wb3 + (size_t)k8*3*2048;
          const uint4 fv4 = *(const uint4*)&sfh[k8*8];
          uint4 ww;
          ww = *(const uint4*)(wk + 0*2048); DOT4(ar, ww, fv4);
          ww = *(const uint4*)(wk + 1*2048); DOT4(az, ww, fv4);
          ww = *(const uint4*)(wk + 2*2048); DOT4(ani, ww, fv4);
        }
      }
    }
    if (kq) {
      sred[kq-1][0][j]=ar; sred[kq-1][1][j]=az; sred[kq-1][2][j]=ani;
      sred[kq-1][3][j]=anh; sred[kq-1][4][j]=gr; sred[kq-1][5][j]=gz;
      sred[kq-1][6][j]=gh;
    }
    __syncthreads();                      // BAR_A
    float grt=0, gzt=0, ght=0;
    if (kq == 0) {
      const float art  = ar + sred[0][0][j]+sred[1][0][j]+sred[2][0][j]
                       + ge_r + b_rc;
      const float azt  = az + sred[0][1][j]+sred[1][1][j]+sred[2][1][j]
                       + ge_z + b_zc;
      const float anit = ani + sred[0][2][j]+sred[1][2][j]+sred[2][2][j]
                       + ge_n + b_nc;
      const float anht = anh + sred[0][3][j]+sred[1][3][j]+sred[2][3][j]
                       + b_nhc;
      grt = gr + sred[0][4][j]+sred[1][4][j]+sred[2][4][j];
      gzt = gz + sred[0][5][j]+sred[1][5][j]+sred[2][5][j];
      ght = gh + sred[0][6][j]+sred[1][6][j]+sred[2][6][j];
      const float r = sigm_(art), z = sigm_(azt);
      const float n = tanhf(anit + r*anht);
      const float cn = fminf((1.f-z)*n + z*scf[j], CLIPV);
      scf[j] = cn; sch[j] = (f16)cn;
      float p0=uwm0*cn, p1=uwm1*cn, p2=uwv0*cn, p3=uwv1*cn;
      #pragma unroll
      for (int s = 32; s; s >>= 1) {
        p0+=__shfl_down(p0,s); p1+=__shfl_down(p1,s);
        p2+=__shfl_down(p2,s); p3+=__shfl_down(p3,s);
      }
      if (lane == 0) {
        s_ured[wv][0]=p0; s_ured[wv][1]=p1; s_ured[wv][2]=p2; s_ured[wv][3]=p3;
      }
    }
    __syncthreads();                      // BAR_B
    if (kq == 0) {
      const float sm0 = s_ured[0][0]+s_ured[1][0]+s_ured[2][0]+s_ured[3][0];
      const float sm1 = s_ured[0][1]+s_ured[1][1]+s_ured[2][1]+s_ured[3][1];
      const float sm2 = s_ured[0][2]+s_ured[1][2]+s_ured[2][2]+s_ured[3][2];
      const float sm3 = s_ured[0][3]+s_ured[1][3]+s_ured[2][3]+s_ured[3][3];
      const float lv0 = fmaxf(sm2 + uvb0, LVMIN_);
      const float lv1 = fmaxf(sm3 + uvb1, LVMIN_);
      const float u0 = ev.x*expf(0.5f*lv0) + sm0 + umb0;
      const float u1 = ev.y*expf(0.5f*lv1) + sm1 + umb1;
      const float rg = sigm_(grt + gur0*u0 + gur1*u1 + b_rg);
      const float zg = sigm_(gzt + guz0*u0 + guz1*u1 + b_zg);
      const float ng = tanhf(gun0*u0 + gun1*u1 + b_ng + rg*(ght + b_nhg));
      const float gn = fminf((1.f-zg)*ng + zg*sgf[j], CLIPV);
      sgf[j] = gn; sgh[j] = (f16)gn;
    }
    __syncthreads();                      // BAR_C
    {
      const int d = tid & 63, grp = tid >> 6;
      float fp = 0.f;
      #pragma unroll
      for (int k2 = grp*8; k2 < grp*8+8; ++k2)
        fp = dot2_(*(const f16x2*)(sfac2 + (size_t)(k2*64 + d)*2),
                   *(const f16x2*)(&sgh[k2*2]), fp);
      s_fred[grp][d] = fp;
    }
    __syncthreads();                      // BAR_D
    if (tid < 64) {
      float fv = facb_l;
      #pragma unroll
      for (int g = 0; g < 16; ++g) fv += s_fred[g][tid];
      float* fo = (float*)(a.fout + ((size_t)b*T_ + t)*512);
      fo[tid] = fv;
      sfh[tid] = (f16)fv;
    }
    __syncthreads();                      // BAR_E
  }
  if (kq == 0) {
    a.S[(size_t)b*512 + j]       = sgf[j];
    a.S[(size_t)b*512 + 256 + j] = scf[j];
  }
}

// ------------------------- deferred output MLP -------------------------------

struct MlpArgs { const char* fbase; const float* f1w; const float* f1b;
                 const float* clw; const float* clb; float* out; };

__global__ __launch_bounds__(256) void k_mlp(MlpArgs a) {
  __shared__ float sf1T[64*80];     // [k][d]
  __shared__ float sclT[80*64];     // [kh][o]
  __shared__ float sfv[4][64];
  __shared__ float sh1[4][80];
  const int b = blockIdx.y, t0 = blockIdx.x*8;
  const int j = threadIdx.x, lane = j & 63, w = j >> 6;
  for (int idx = j; idx < 5120; idx += 256) {
    const int k = idx / 80, d = idx % 80;
    sf1T[idx] = a.f1w[(size_t)d*64 + k];
  }
  for (int idx = j; idx < 5120; idx += 256) {
    const int kh = idx >> 6, o = idx & 63;
    sclT[idx] = a.clw[(size_t)o*80 + kh];
  }
  __syncthreads();
  for (int ti = 0; ti < 2; ++ti) {
    const int t = t0 + w*2 + ti;
    const float* fp = (const float*)(a.fbase + ((size_t)b*T_ + t)*512);
    sfv[w][lane] = fp[lane];
    __syncthreads();
    float h1a = a.f1b[lane];
    float h1b = (lane < 16) ? a.f1b[64 + lane] : 0.f;
    for (int k = 0; k < 64; ++k) {
      const float fv = sfv[w][k];
      h1a += sf1T[k*80 + lane]*fv;
      if (lane < 16) h1b += sf1T[k*80 + 64 + lane]*fv;
    }
    sh1[w][lane] = fmaxf(h1a, 0.f);
    if (lane < 16) sh1[w][64 + lane] = fmaxf(h1b, 0.f);
    __syncthreads();
    float o = a.clb[lane];
    for (int kh = 0; kh < H1_; ++kh)
      o += sclT[kh*64 + lane]*sh1[w][kh];
    a.out[((size_t)b*T_ + t)*DOUT_ + lane] = o;
    __syncthreads();
  }
}

// ------------------------- host launcher ------------------------------------

extern "C" void kernel_launch(void* const* d_in, const int* in_sizes, int n_in,
                              void* d_out, int out_size, void* d_ws, size_t ws_size,
                              hipStream_t stream) {
  const float* x      = (const float*)d_in[0];
  const float* eps_g0 = (const float*)d_in[1];
  const float* eps_u  = (const float*)d_in[2];
  const float* egf_wih = (const float*)d_in[3],  *egf_whh = (const float*)d_in[4];
  const float* egf_bih = (const float*)d_in[5],  *egf_bhh = (const float*)d_in[6];
  const float* egb_wih = (const float*)d_in[7],  *egb_whh = (const float*)d_in[8];
  const float* egb_bih = (const float*)d_in[9],  *egb_bhh = (const float*)d_in[10];
  const float* ecf_wih = (const float*)d_in[11], *ecf_whh = (const float*)d_in[12];
  const float* ecf_bih = (const float*)d_in[13], *ecf_bhh = (const float*)d_in[14];
  const float* ecb_wih = (const float*)d_in[15], *ecb_whh = (const float*)d_in[16];
  const float* ecb_bih = (const float*)d_in[17], *ecb_bhh = (const float*)d_in[18];
  const float* con_wih = (const float*)d_in[19], *con_whh = (const float*)d_in[20];
  const float* con_bih = (const float*)d_in[21], *con_bhh = (const float*)d_in[22];
  const float* gen_wih = (const float*)d_in[23], *gen_whh = (const float*)d_in[24];
  const float* gen_bih = (const float*)d_in[25], *gen_bhh = (const float*)d_in[26];
  const float* g0m_w = (const float*)d_in[27], *g0m_b = (const float*)d_in[28];
  const float* g0v_w = (const float*)d_in[29], *g0v_b = (const float*)d_in[30];
  const float* um_w = (const float*)d_in[31], *um_b = (const float*)d_in[32];
  const float* uv_w = (const float*)d_in[33], *uv_b = (const float*)d_in[34];
  const float* fac_w = (const float*)d_in[35], *fac_b = (const float*)d_in[36];
  const float* f1_w = (const float*)d_in[37], *f1_b = (const float*)d_in[38];
  const float* cl_w = (const float*)d_in[39], *cl_b = (const float*)d_in[40];
  float* out = (float*)d_out;
  (void)ws_size; (void)in_sizes; (void)n_in; (void)out_size;

  // Workspace layout (160,407,552 B <= 167,297,024):
  //   efS  [B][T][256] f16    65,536,000  (prefix aliased by f32 f[64])
  //   ebS                     65,536,000
  //   ge   [B][TC][768] f16   25,165,824
  //   wenc [4][245760] f16     1,966,080
  //   wg6  [393216] f16          786,432
  //   w3   [49152]  f16           98,304
  //   w2   [393216] f16          786,432
  //   hgF/hgB f32                262,144
  //   S    [B][512] f32          262,144
  //   bias8 [256][8] f32           8,192
  char* ws = (char*)d_ws;
  f16* efS   = (f16*)(ws + 0);
  f16* ebS   = (f16*)(ws + 65536000ul);
  f16* geb   = (f16*)(ws + 131072000ul);
  f16* wenc  = (f16*)(ws + 156237824ul);
  f16* wg6   = (f16*)(ws + 158203904ul);
  f16* w3    = (f16*)(ws + 158990336ul);
  f16* w2    = (f16*)(ws + 159088640ul);
  float* hgF = (float*)(ws + 159875072ul);
  float* hgB = (float*)(ws + 160006144ul);
  float* S   = (float*)(ws + 160137216ul);
  float* bias8 = (float*)(ws + 160399360ul);

  PEncArgs pe;
  pe.wih[0] = egf_wih; pe.whh[0] = egf_whh;
  pe.wih[1] = ecf_wih; pe.whh[1] = ecf_whh;
  pe.wih[2] = egb_wih; pe.whh[2] = egb_whh;
  pe.wih[3] = ecb_wih; pe.whh[3] = ecb_whh;
  pe.dst = wenc;
  k_prep_enc<<<dim3(960, 4), 256, 0, stream>>>(pe);
  k_prep_gen<<<1536, 256, 0, stream>>>(con_whh, gen_whh, wg6);
  k_prep_w3<<<192, 256, 0, stream>>>(con_wih, w3);
  k_prep_w2<<<1536, 256, 0, stream>>>(con_wih, w2);
  k_prep_bias<<<1, 256, 0, stream>>>(con_bih, con_bhh, gen_bih, gen_bhh, bias8);

  EncArgs ea;
  ea.x = x;
  ea.bih[0] = egf_bih; ea.bhh[0] = egf_bhh;
  ea.bih[1] = ecf_bih; ea.bhh[1] = ecf_bhh;
  ea.bih[2] = egb_bih; ea.bhh[2] = egb_bhh;
  ea.bih[3] = ecb_bih; ea.bhh[3] = ecb_bhh;
  ea.wenc = wenc; ea.efS = efS; ea.ebS = ebS; ea.hgF = hgF; ea.hgB = hgB;
  k_encoder<<<256, 1024, 0, stream>>>(ea);

  k_g0<<<128, 256, 0, stream>>>(hgF, hgB, g0m_w, g0m_b, g0v_w, g0v_b, eps_g0, S);

  for (int c = 0; c < NCHUNK_; ++c) {
    GeArgs ga; ga.efS = efS; ga.ebS = ebS; ga.w2 = w2; ga.ge = geb; ga.t0 = c*TC_;
    k_ge<<<dim3(16, B_), 256, 0, stream>>>(ga);
    GenArgs gn;
    gn.wg6 = wg6; gn.w3 = w3; gn.ge = geb; gn.bias8 = bias8; gn.genwih = gen_wih;
    gn.umw = um_w; gn.umb = um_b; gn.uvw = uv_w; gn.uvb = uv_b;
    gn.epsu = eps_u; gn.facw = fac_w; gn.facb = fac_b;
    gn.S = S; gn.fout = (char*)ws;
    gn.t0 = c*TC_;
    gn.tcnt = (T_ - c*TC_ < TC_) ? (T_ - c*TC_) : TC_;
    k_gen<<<128, 1024, 0, stream>>>(gn);
  }

  MlpArgs ma; ma.fbase = (const char*)ws; ma.f1w = f1_w; ma.f1b = f1_b;
  ma.clw = cl_w; ma.clb = cl_b; ma.out = out;
  k_mlp<<<dim3(125, B_), 256, 0, stream>>>(ma);
}

// Round 12
// 13784.850 us; speedup vs baseline: 1.1328x; 1.1328x over previous
//
#include <hip/hip_runtime.h>
#include <stdint.h>
#include <stddef.h>

// ---------------------------------------------------------------------------
// LFADS forward on MI355X — round 19.
// R18 null: launch_bounds(1024,4) is an occupancy MINIMUM, not a register
// directive — allocator stays at 64 VGPR and spills. Design within 64:
//  - enc: keep R18 (4.5ms best measured; its spill reloads are L2-cheap)
//  - gen: move 18 loop-invariant per-j floats (bias8/genwih/um/uv) to an
//    18KB LDS table (read post-barrier), shrink weight cache to 6 uint4
//    (24 VGPR) -> total ~56 regs, NO spill; stream 884->786 KB/step.
// ---------------------------------------------------------------------------

#define B_    128
#define T_    1000
#define DIN_  64
#define E_    256
#define F_    64
#define H1_   80
#define DOUT_ 64
#define CLIPV 5.0f
#define LVMIN_ (-9.210340371976182f)
#define TC_   128
#define NCHUNK_ 8

typedef _Float16 f16;
typedef _Float16 f16x2 __attribute__((ext_vector_type(2)));

__device__ __forceinline__ float sigm_(float x) { return 1.0f/(1.0f + expf(-x)); }

__device__ __forceinline__ float dot2_(f16x2 a, f16x2 b, float c) {
  asm("v_dot2_f32_f16 %0, %1, %2, %0" : "+v"(c) : "v"(a), "v"(b));
  return c;
}
#define P0_(Wv) __builtin_bit_cast(f16x2, (Wv).x)
#define P1_(Wv) __builtin_bit_cast(f16x2, (Wv).y)
#define P2_(Wv) __builtin_bit_cast(f16x2, (Wv).z)
#define P3_(Wv) __builtin_bit_cast(f16x2, (Wv).w)
#define DOT4(Av, Wv, Hv) \
  Av = dot2_(P0_(Wv), P0_(Hv), Av); Av = dot2_(P1_(Wv), P1_(Hv), Av); \
  Av = dot2_(P2_(Wv), P2_(Hv), Av); Av = dot2_(P3_(Wv), P3_(Hv), Av);

// ------------------------- weight prep --------------------------------------
// Encoder weights per chain fp16: ih [k8<8][m<3][j<256][i<8], then
// hh [k8<32][m<3][j<256][i<8]  (49152 + 196608 = 245760 halfs)

struct PEncArgs { const float* wih[4]; const float* whh[4]; f16* dst; };

__global__ __launch_bounds__(256) void k_prep_enc(PEncArgs a) {
  const int chain = blockIdx.y;
  const int idx = blockIdx.x*256 + threadIdx.x;     // < 245760
  float v;
  if (idx < 49152) {
    const int i = idx & 7, j = (idx >> 3) & 255;
    const int r = idx >> 11;                        // < 24
    const int m = r % 3, k8 = r / 3;                // k8 < 8
    v = a.wih[chain][((size_t)(m*E_ + j))*DIN_ + k8*8 + i];
  } else {
    const int t = idx - 49152;
    const int i = t & 7, j = (t >> 3) & 255;
    const int r = t >> 11;                          // < 96
    const int m = r % 3, k8 = r / 3;                // k8 < 32
    v = a.whh[chain][((size_t)(m*E_ + j))*E_ + k8*8 + i];
  }
  a.dst[(size_t)chain*245760 + idx] = (f16)v;
}

// Generator recurrent weights fp16: [k8<32][m<6][j<256][i<8]
// m 0..2 = con_whh r/z/n (dot c); m 3..5 = gen_whh r/z/n (dot g)
__global__ __launch_bounds__(256) void k_prep_gen(const float* __restrict__ conwhh,
                                                  const float* __restrict__ genwhh,
                                                  f16* __restrict__ wg6) {
  const int idx = blockIdx.x*256 + threadIdx.x;     // < 393216
  const int i = idx & 7, j = (idx >> 3) & 255;
  const int r = idx >> 11;                          // < 192
  const int m = r % 6, k8 = r / 6;                  // k8 < 32
  const int k = k8*8 + i;
  const float v = (m < 3) ? conwhh[(size_t)(m*E_ + j)*E_ + k]
                          : genwhh[(size_t)((m-3)*E_ + j)*E_ + k];
  wg6[idx] = (f16)v;
}

// W3 = con_wih[:, 512:576] fp16: [k8<8][m<3][j<256][i<8] (dot f)
__global__ __launch_bounds__(256) void k_prep_w3(const float* __restrict__ conwih,
                                                 f16* __restrict__ w3) {
  const int idx = blockIdx.x*256 + threadIdx.x;     // < 49152
  const int i = idx & 7, j = (idx >> 3) & 255;
  const int r = idx >> 11;                          // < 24
  const int m = r % 3, k8 = r / 3;                  // k8 < 8
  w3[idx] = (f16)conwih[(size_t)(m*E_ + j)*576 + 512 + k8*8 + i];
}

// W2 = con_wih[:, 0:512] fp16: [k8<64][m<3][j<256][i<8]
__global__ __launch_bounds__(256) void k_prep_w2(const float* __restrict__ conwih,
                                                 f16* __restrict__ w2) {
  const int idx = blockIdx.x*256 + threadIdx.x;     // < 393216
  const int i = idx & 7, j = (idx >> 3) & 255;
  const int r = idx >> 11;                          // < 192
  const int m = r % 3, k8 = r / 3;                  // k8 < 64
  w2[idx] = (f16)conwih[(size_t)(m*E_ + j)*576 + k8*8 + i];
}

// Per-feature fused biases: [j][8] f32 (fac_b flows through f)
__global__ void k_prep_bias(const float* __restrict__ conbih,
                            const float* __restrict__ conbhh,
                            const float* __restrict__ genbih,
                            const float* __restrict__ genbhh,
                            float* __restrict__ bias8) {
  const int j = threadIdx.x;
  float* o = bias8 + j*8;
  o[0] = conbih[j]      + conbhh[j];      // con r
  o[1] = conbih[E_+j]   + conbhh[E_+j];   // con z
  o[2] = conbih[2*E_+j];                  // con n (input)
  o[3] = conbhh[2*E_+j];                  // con n (hidden)
  o[4] = genbih[j]      + genbhh[j];      // gen r
  o[5] = genbih[E_+j]   + genbhh[E_+j];   // gen z
  o[6] = genbih[2*E_+j];                  // gen n (input)
  o[7] = genbhh[2*E_+j];                  // gen n (hidden)
}

// ------------------------- encoder (R18 verbatim) ----------------------------
// 256 blocks = 4 chains x 64 pairs (2 batches); 1024 threads = (j, kq<4)

struct EncArgs {
  const float* x;                       // [B][T][64]
  const float* bih[4]; const float* bhh[4];
  const f16* wenc;                      // [4][245760]
  f16* efS; f16* ebS;                   // [B][T][256]
  float* hgF; float* hgB;               // [128][256]
};

__global__ __launch_bounds__(1024, 4) void k_encoder(EncArgs a) {
  __shared__ __align__(16) f16 shh[2][256];
  __shared__ __align__(16) f16 sxh[2][64];
  __shared__ float shf[2][256];
  __shared__ float sred[3][6][256];           // kq 1..3 partials [q*3+g][j]
  const int chain = blockIdx.x >> 6;
  const int pair  = blockIdx.x & 63;
  const int b0 = pair*2;
  const int j  = threadIdx.x & 255;
  const int kq = threadIdx.x >> 8;
  const bool bwd = (chain >= 2);
  const f16* Wih = a.wenc + (size_t)chain*245760;
  const f16* Whh = Wih + 49152;
  f16* st = (chain==1) ? a.efS : (chain==3 ? a.ebS : nullptr);
  float* hgout = (chain==0) ? a.hgF : (chain==2 ? a.hgB : nullptr);

  float br=0,bz=0,bni=0,bnh=0;
  if (kq == 0) {
    br  = a.bih[chain][j]      + a.bhh[chain][j];
    bz  = a.bih[chain][E_+j]   + a.bhh[chain][E_+j];
    bni = a.bih[chain][2*E_+j];
    bnh = a.bhh[chain][2*E_+j];
  }
  if (threadIdx.x < 512) {
    shf[threadIdx.x>>8][threadIdx.x&255] = 0.f;
    shh[threadIdx.x>>8][threadIdx.x&255] = (f16)0.f;
  }
  float xv = 0.f;
  if (kq == 0 && j < 128) {
    const int q = j >> 6, k = j & 63;
    const int tt0 = bwd ? (T_-1) : 0;
    xv = a.x[((size_t)(b0+q)*T_ + tt0)*DIN_ + k];
  }
  const f16* wpi = Wih + (size_t)j*8;
  const f16* wph = Whh + (size_t)j*8;
  const int ks1 = 2 + (kq-1)*10;              // kq>=1 stream base

  // ---- loop-invariant register weight cache: 18 uint4 (6 triples) ----
  uint4 RC[18];
  if (kq == 0) {
    #pragma unroll
    for (int i = 0; i < 18; ++i)
      RC[i] = *(const uint4*)(wpi + (size_t)i*2048);        // ih k8 0..5
  } else {
    #pragma unroll
    for (int i = 0; i < 18; ++i)
      RC[i] = *(const uint4*)(wph + (size_t)(ks1*3 + i)*2048); // hh ks1..ks1+5
  }

  for (int t = 0; t < T_; ++t) {
    const int tt = bwd ? (T_-1-t) : t;
    if (kq == 0 && j < 128) sxh[j>>6][j&63] = (f16)xv;
    __syncthreads();                          // BAR1: x_t + h_{t-1} published
    if (kq == 0 && j < 128 && t+1 < T_) {
      const int q = j >> 6, k = j & 63;
      const int tn = bwd ? (T_-2-t) : (t+1);
      xv = a.x[((size_t)(b0+q)*T_ + tn)*DIN_ + k];
    }
    float ar[2]={0,0}, az[2]={0,0}, ani[2]={0,0}, anh[2]={0,0};
    if (kq == 0) {
      // cached ih k8 0..5
      #pragma unroll
      for (int k8 = 0; k8 < 6; ++k8) {
        #pragma unroll
        for (int q = 0; q < 2; ++q) {
          const uint4 xq = *(const uint4*)(&sxh[q][k8*8]);
          DOT4(ar[q], RC[k8*3+0], xq); DOT4(az[q], RC[k8*3+1], xq);
          DOT4(ani[q], RC[k8*3+2], xq);
        }
      }
      // streamed ih k8 6..7
      #pragma unroll
      for (int k8 = 6; k8 < 8; ++k8) {
        const uint4 c0 = *(const uint4*)(wpi + (size_t)(k8*3+0)*2048);
        const uint4 c1 = *(const uint4*)(wpi + (size_t)(k8*3+1)*2048);
        const uint4 c2 = *(const uint4*)(wpi + (size_t)(k8*3+2)*2048);
        #pragma unroll
        for (int q = 0; q < 2; ++q) {
          const uint4 xq = *(const uint4*)(&sxh[q][k8*8]);
          DOT4(ar[q], c0, xq); DOT4(az[q], c1, xq); DOT4(ani[q], c2, xq);
        }
      }
      // streamed hh k8 0..1
      #pragma unroll
      for (int k8 = 0; k8 < 2; ++k8) {
        const uint4 c0 = *(const uint4*)(wph + (size_t)(k8*3+0)*2048);
        const uint4 c1 = *(const uint4*)(wph + (size_t)(k8*3+1)*2048);
        const uint4 c2 = *(const uint4*)(wph + (size_t)(k8*3+2)*2048);
        #pragma unroll
        for (int q = 0; q < 2; ++q) {
          const uint4 hq = *(const uint4*)(&shh[q][k8*8]);
          DOT4(ar[q], c0, hq); DOT4(az[q], c1, hq); DOT4(anh[q], c2, hq);
        }
      }
    } else {
      // cached hh ks1..ks1+5
      #pragma unroll
      for (int i = 0; i < 6; ++i) {
        const int k8 = ks1 + i;
        #pragma unroll
        for (int q = 0; q < 2; ++q) {
          const uint4 hq = *(const uint4*)(&shh[q][k8*8]);
          DOT4(ar[q], RC[i*3+0], hq); DOT4(az[q], RC[i*3+1], hq);
          DOT4(anh[q], RC[i*3+2], hq);
        }
      }
      // streamed hh ks1+6..ks1+9
      #pragma unroll 2
      for (int kk = 6; kk < 10; ++kk) {
        const int k8 = ks1 + kk;
        const uint4 c0 = *(const uint4*)(wph + (size_t)(k8*3+0)*2048);
        const uint4 c1 = *(const uint4*)(wph + (size_t)(k8*3+1)*2048);
        const uint4 c2 = *(const uint4*)(wph + (size_t)(k8*3+2)*2048);
        #pragma unroll
        for (int q = 0; q < 2; ++q) {
          const uint4 hq = *(const uint4*)(&shh[q][k8*8]);
          DOT4(ar[q], c0, hq); DOT4(az[q], c1, hq); DOT4(anh[q], c2, hq);
        }
      }
      #pragma unroll
      for (int q = 0; q < 2; ++q) {
        sred[kq-1][q*3+0][j] = ar[q];
        sred[kq-1][q*3+1][j] = az[q];
        sred[kq-1][q*3+2][j] = anh[q];
      }
    }
    __syncthreads();                          // BAR2
    if (kq == 0) {
      #pragma unroll
      for (int q = 0; q < 2; ++q) {
        const float arq  = ar[q]  + sred[0][q*3+0][j] + sred[1][q*3+0][j]
                         + sred[2][q*3+0][j] + br;
        const float azq  = az[q]  + sred[0][q*3+1][j] + sred[1][q*3+1][j]
                         + sred[2][q*3+1][j] + bz;
        const float anhq = anh[q] + sred[0][q*3+2][j] + sred[1][q*3+2][j]
                         + sred[2][q*3+2][j] + bnh;
        const float r = sigm_(arq);
        const float z = sigm_(azq);
        const float n = tanhf(ani[q] + bni + r*anhq);
        const float hn = fminf((1.f - z)*n + z*shf[q][j], CLIPV);
        shf[q][j] = hn;
        shh[q][j] = (f16)hn;
        if (st) st[((size_t)(b0+q)*T_ + tt)*E_ + j] = (f16)hn;
        if (hgout && t == T_-1) hgout[(size_t)(b0+q)*E_ + j] = hn;
      }
    }
  }
}

// ------------------------- g0 sample ----------------------------------------

__global__ __launch_bounds__(256) void k_g0(const float* __restrict__ hgF,
                                            const float* __restrict__ hgB,
                                            const float* __restrict__ g0mw,
                                            const float* __restrict__ g0mb,
                                            const float* __restrict__ g0vw,
                                            const float* __restrict__ g0vb,
                                            const float* __restrict__ epsg0,
                                            float* __restrict__ S) {
  __shared__ __align__(16) float sf[E_], sb[E_];
  const int b = blockIdx.x, k = threadIdx.x;
  sf[k] = hgF[(size_t)b*E_ + k];
  sb[k] = hgB[(size_t)b*E_ + k];
  __syncthreads();
  const float* mr = g0mw + (size_t)k*512;
  const float* vr = g0vw + (size_t)k*512;
  float dm = 0.f, dv = 0.f;
  for (int i = 0; i < E_; i += 4) {
    const float4 m4 = *(const float4*)(mr + i);
    const float4 v4 = *(const float4*)(vr + i);
    const float4 h4 = *(const float4*)&sf[i];
    dm += m4.x*h4.x + m4.y*h4.y + m4.z*h4.z + m4.w*h4.w;
    dv += v4.x*h4.x + v4.y*h4.y + v4.z*h4.z + v4.w*h4.w;
  }
  for (int i = 0; i < E_; i += 4) {
    const float4 m4 = *(const float4*)(mr + 256 + i);
    const float4 v4 = *(const float4*)(vr + 256 + i);
    const float4 h4 = *(const float4*)&sb[i];
    dm += m4.x*h4.x + m4.y*h4.y + m4.z*h4.z + m4.w*h4.w;
    dv += v4.x*h4.x + v4.y*h4.y + v4.z*h4.z + v4.w*h4.w;
  }
  const float lv = fmaxf(dv + g0vb[k], LVMIN_);
  const float g  = epsg0[(size_t)b*E_ + k]*expf(0.5f*lv) + dm + g0mb[k];
  S[(size_t)b*512 + k]       = g;
  S[(size_t)b*512 + 256 + k] = 0.f;
}

// ------------------------- ge chunk GEMM ------------------------------------

struct GeArgs { const f16* efS; const f16* ebS; const f16* w2; f16* ge; int t0; };

__global__ __launch_bounds__(256) void k_ge(GeArgs a) {
  __shared__ __align__(16) f16 A[8][512];
  const int tile = blockIdx.x, b = blockIdx.y;
  const int tl0 = tile*8;
  const int j = threadIdx.x;
  for (int r = 0; r < 16; ++r) {
    const int idx = r*256 + j;
    const int tt = idx >> 9, k = idx & 511;
    const int t = a.t0 + tl0 + tt;
    f16 v = (f16)0.f;
    if (t < T_)
      v = (k < 256) ? a.efS[((size_t)b*T_ + t)*E_ + k]
                    : a.ebS[((size_t)b*T_ + t)*E_ + (k-256)];
    A[tt][k] = v;
  }
  __syncthreads();
  float acc[3][8];
  #pragma unroll
  for (int m = 0; m < 3; ++m)
    #pragma unroll
    for (int tt = 0; tt < 8; ++tt) acc[m][tt] = 0.f;
  const f16* wb = a.w2 + (size_t)j*8;
  #pragma unroll 2
  for (int k8 = 0; k8 < 64; ++k8) {
    uint4 av[8];
    #pragma unroll
    for (int tt = 0; tt < 8; ++tt) av[tt] = *(const uint4*)&A[tt][k8*8];
    #pragma unroll
    for (int m = 0; m < 3; ++m) {
      const uint4 wm = *(const uint4*)(wb + (size_t)(k8*3+m)*2048);
      DOT4(acc[m][0], wm, av[0]); DOT4(acc[m][1], wm, av[1]);
      DOT4(acc[m][2], wm, av[2]); DOT4(acc[m][3], wm, av[3]);
      DOT4(acc[m][4], wm, av[4]); DOT4(acc[m][5], wm, av[5]);
      DOT4(acc[m][6], wm, av[6]); DOT4(acc[m][7], wm, av[7]);
    }
  }
  #pragma unroll
  for (int m = 0; m < 3; ++m)
    #pragma unroll
    for (int tt = 0; tt < 8; ++tt)
      a.ge[((size_t)b*TC_ + tl0+tt)*768 + m*E_ + j] = (f16)acc[m][tt];
}

// ------------------------- generator ----------------------------------------
// 128 blocks = 1 batch each; 1024 threads = (j, kq<4)
// kq0: wg6 k8 0-8; kq1: 9-17; kq2: 18-26; kq3: 27-31 + W3 (f part)
// Per-j loop-invariants (bias8/genwih/um/uv = 18 f32) live in LDS; weight
// cache = 1 hextuple (6 uint4 = 24 VGPR) -> fits 64-VGPR budget, no spill.

struct GenArgs {
  const f16* wg6;          // [32][6][256][8]
  const f16* w3;           // [8][3][256][8]
  const f16* ge;           // [B][TC_][768]
  const float* bias8;      // [256][8]
  const float* genwih;     // [768][2]
  const float* umw; const float* umb; const float* uvw; const float* uvb;
  const float* epsu;       // [B][T][2]
  const float* facw; const float* facb;
  float* S;                // [B][512]
  char* fout;              // f32 f[64] at byte (b*T+t)*512 (aliases efS)
  int t0, tcnt;
};

__global__ __launch_bounds__(1024, 4) void k_gen(GenArgs a) {
  __shared__ __align__(16) f16 sgh[256], sch[256], sfh[64];
  __shared__ float sgf[256], scf[256];
  __shared__ float sred[3][7][256];            // kq1..3: ar,az,ani,anh,gr,gz,gh
  __shared__ float s_ured[4][4];
  __shared__ __align__(16) f16 sfac2[16384];   // [k2<128][d<64][2]
  __shared__ float s_fred[16][64];
  __shared__ float sb18[256][18];              // per-j invariants (18KB)
  const int b = blockIdx.x;
  const int tid = threadIdx.x;
  const int j  = tid & 255;
  const int kq = tid >> 8;
  const int lane = tid & 63;
  const int wv = (tid >> 6) & 3;

  for (int idx = tid; idx < 16384; idx += 1024) {
    const int k = idx >> 6, d = idx & 63;
    sfac2[(size_t)(k>>1)*128 + d*2 + (k&1)] = (f16)a.facw[(size_t)d*E_ + k];
  }
  if (kq == 0) {
    const float g0v = a.S[(size_t)b*512 + j];
    const float c0v = a.S[(size_t)b*512 + 256 + j];
    sgf[j] = g0v; sgh[j] = (f16)g0v;
    scf[j] = c0v; sch[j] = (f16)c0v;
    // per-j invariants -> LDS
    const float4 b0 = *(const float4*)(a.bias8 + j*8);
    const float4 b1 = *(const float4*)(a.bias8 + j*8 + 4);
    sb18[j][0]=b0.x; sb18[j][1]=b0.y; sb18[j][2]=b0.z; sb18[j][3]=b0.w;
    sb18[j][4]=b1.x; sb18[j][5]=b1.y; sb18[j][6]=b1.z; sb18[j][7]=b1.w;
    sb18[j][8]  = a.genwih[j*2];        sb18[j][9]  = a.genwih[j*2+1];
    sb18[j][10] = a.genwih[(E_+j)*2];   sb18[j][11] = a.genwih[(E_+j)*2+1];
    sb18[j][12] = a.genwih[(2*E_+j)*2]; sb18[j][13] = a.genwih[(2*E_+j)*2+1];
    sb18[j][14] = a.umw[j];  sb18[j][15] = a.umw[E_+j];
    sb18[j][16] = a.uvw[j];  sb18[j][17] = a.uvw[E_+j];
  }
  const float umb0 = a.umb[0], umb1 = a.umb[1];     // uniform -> SGPR
  const float uvb0 = a.uvb[0], uvb1 = a.uvb[1];
  float facb_l = 0.f;
  if (tid < 64) facb_l = a.facb[tid];
  const f16* wb6 = a.wg6 + (size_t)j*8;
  const f16* wb3 = a.w3  + (size_t)j*8;
  const int ks = kq*9;                      // 0,9,18,27
  const int ke = (kq==3) ? 32 : ks+9;

  // ---- loop-invariant register cache: 1 k8-hextuple = 6 uint4 ----
  uint4 GC[6];
  #pragma unroll
  for (int m = 0; m < 6; ++m)
    GC[m] = *(const uint4*)(wb6 + ((size_t)ks*6 + m)*2048);
  __syncthreads();

  // prologue: f_prev = fac_w @ g_prev + fac_b
  {
    const int d = tid & 63, grp = tid >> 6;
    float fp = 0.f;
    #pragma unroll
    for (int k2 = grp*8; k2 < grp*8+8; ++k2)
      fp = dot2_(*(const f16x2*)(sfac2 + (size_t)(k2*64 + d)*2),
                 *(const f16x2*)(&sgh[k2*2]), fp);
    s_fred[grp][d] = fp;
  }
  __syncthreads();
  if (tid < 64) {
    float fv = facb_l;
    #pragma unroll
    for (int g = 0; g < 16; ++g) fv += s_fred[g][tid];
    sfh[tid] = (f16)fv;
  }
  __syncthreads();

  for (int tl = 0; tl < a.tcnt; ++tl) {
    const int t = a.t0 + tl;
    float ge_r=0, ge_z=0, ge_n=0;
    float2 ev = {0,0};
    if (kq == 0) {
      const f16* gp = a.ge + ((size_t)b*TC_ + tl)*768;
      ge_r = (float)gp[j]; ge_z = (float)gp[E_+j]; ge_n = (float)gp[2*E_+j];
      ev = *(const float2*)(a.epsu + ((size_t)b*T_ + t)*2);
    }
    float ar=0, az=0, ani=0, anh=0, gr=0, gz=0, gh=0;
    {
      // cached k8 = ks
      {
        const uint4 gv = *(const uint4*)&sgh[ks*8];
        const uint4 cv = *(const uint4*)&sch[ks*8];
        DOT4(ar,  GC[0], cv);
        DOT4(az,  GC[1], cv);
        DOT4(anh, GC[2], cv);
        DOT4(gr,  GC[3], gv);
        DOT4(gz,  GC[4], gv);
        DOT4(gh,  GC[5], gv);
      }
      // streamed k8 = ks+1 .. ke-1
      #pragma unroll 2
      for (int k8 = ks+1; k8 < ke; ++k8) {
        const f16* wk = wb6 + (size_t)k8*6*2048;
        const uint4 gv = *(const uint4*)&sgh[k8*8];
        const uint4 cv = *(const uint4*)&sch[k8*8];
        uint4 ww;
        ww = *(const uint4*)(wk + 0*2048); DOT4(ar, ww, cv);
        ww = *(const uint4*)(wk + 1*2048); DOT4(az, ww, cv);
        ww = *(const uint4*)(wk + 2*2048); DOT4(anh, ww, cv);
        ww = *(const uint4*)(wk + 3*2048); DOT4(gr, ww, gv);
        ww = *(const uint4*)(wk + 4*2048); DOT4(gz, ww, gv);
        ww = *(const uint4*)(wk + 5*2048); DOT4(gh, ww, gv);
      }
      if (kq == 3) {
        #pragma unroll 2
        for (int k8 = 0; k8 < 8; ++k8) {
          const f16* wk = wb3 + (size_t)k8*3*2048;
          const uint4 fv4 = *(const uint4*)&sfh[k8*8];
          uint4 ww;
          ww = *(const uint4*)(wk + 0*2048); DOT4(ar, ww, fv4);
          ww = *(const uint4*)(wk + 1*2048); DOT4(az, ww, fv4);
          ww = *(const uint4*)(wk + 2*2048); DOT4(ani, ww, fv4);
        }
      }
    }
    if (kq) {
      sred[kq-1][0][j]=ar; sred[kq-1][1][j]=az; sred[kq-1][2][j]=ani;
      sred[kq-1][3][j]=anh; sred[kq-1][4][j]=gr; sred[kq-1][5][j]=gz;
      sred[kq-1][6][j]=gh;
    }
    __syncthreads();                      // BAR_A
    float grt=0, gzt=0, ght=0;
    if (kq == 0) {
      const float art  = ar + sred[0][0][j]+sred[1][0][j]+sred[2][0][j]
                       + ge_r + sb18[j][0];
      const float azt  = az + sred[0][1][j]+sred[1][1][j]+sred[2][1][j]
                       + ge_z + sb18[j][1];
      const float anit = ani + sred[0][2][j]+sred[1][2][j]+sred[2][2][j]
                       + ge_n + sb18[j][2];
      const float anht = anh + sred[0][3][j]+sred[1][3][j]+sred[2][3][j]
                       + sb18[j][3];
      grt = gr + sred[0][4][j]+sred[1][4][j]+sred[2][4][j];
      gzt = gz + sred[0][5][j]+sred[1][5][j]+sred[2][5][j];
      ght = gh + sred[0][6][j]+sred[1][6][j]+sred[2][6][j];
      const float r = sigm_(art), z = sigm_(azt);
      const float n = tanhf(anit + r*anht);
      const float cn = fminf((1.f-z)*n + z*scf[j], CLIPV);
      scf[j] = cn; sch[j] = (f16)cn;
      float p0=sb18[j][14]*cn, p1=sb18[j][15]*cn;
      float p2=sb18[j][16]*cn, p3=sb18[j][17]*cn;
      #pragma unroll
      for (int s = 32; s; s >>= 1) {
        p0+=__shfl_down(p0,s); p1+=__shfl_down(p1,s);
        p2+=__shfl_down(p2,s); p3+=__shfl_down(p3,s);
      }
      if (lane == 0) {
        s_ured[wv][0]=p0; s_ured[wv][1]=p1; s_ured[wv][2]=p2; s_ured[wv][3]=p3;
      }
    }
    __syncthreads();                      // BAR_B
    if (kq == 0) {
      const float sm0 = s_ured[0][0]+s_ured[1][0]+s_ured[2][0]+s_ured[3][0];
      const float sm1 = s_ured[0][1]+s_ured[1][1]+s_ured[2][1]+s_ured[3][1];
      const float sm2 = s_ured[0][2]+s_ured[1][2]+s_ured[2][2]+s_ured[3][2];
      const float sm3 = s_ured[0][3]+s_ured[1][3]+s_ured[2][3]+s_ured[3][3];
      const float lv0 = fmaxf(sm2 + uvb0, LVMIN_);
      const float lv1 = fmaxf(sm3 + uvb1, LVMIN_);
      const float u0 = ev.x*expf(0.5f*lv0) + sm0 + umb0;
      const float u1 = ev.y*expf(0.5f*lv1) + sm1 + umb1;
      const float rg = sigm_(grt + sb18[j][8]*u0  + sb18[j][9]*u1  + sb18[j][4]);
      const float zg = sigm_(gzt + sb18[j][10]*u0 + sb18[j][11]*u1 + sb18[j][5]);
      const float ng = tanhf(sb18[j][12]*u0 + sb18[j][13]*u1 + sb18[j][6]
                             + rg*(ght + sb18[j][7]));
      const float gn = fminf((1.f-zg)*ng + zg*sgf[j], CLIPV);
      sgf[j] = gn; sgh[j] = (f16)gn;
    }
    __syncthreads();                      // BAR_C
    {
      const int d = tid & 63, grp = tid >> 6;
      float fp = 0.f;
      #pragma unroll
      for (int k2 = grp*8; k2 < grp*8+8; ++k2)
        fp = dot2_(*(const f16x2*)(sfac2 + (size_t)(k2*64 + d)*2),
                   *(const f16x2*)(&sgh[k2*2]), fp);
      s_fred[grp][d] = fp;
    }
    __syncthreads();                      // BAR_D
    if (tid < 64) {
      float fv = facb_l;
      #pragma unroll
      for (int g = 0; g < 16; ++g) fv += s_fred[g][tid];
      float* fo = (float*)(a.fout + ((size_t)b*T_ + t)*512);
      fo[tid] = fv;
      sfh[tid] = (f16)fv;
    }
    __syncthreads();                      // BAR_E
  }
  if (kq == 0) {
    a.S[(size_t)b*512 + j]       = sgf[j];
    a.S[(size_t)b*512 + 256 + j] = scf[j];
  }
}

// ------------------------- deferred output MLP -------------------------------

struct MlpArgs { const char* fbase; const float* f1w; const float* f1b;
                 const float* clw; const float* clb; float* out; };

__global__ __launch_bounds__(256) void k_mlp(MlpArgs a) {
  __shared__ float sf1T[64*80];     // [k][d]
  __shared__ float sclT[80*64];     // [kh][o]
  __shared__ float sfv[4][64];
  __shared__ float sh1[4][80];
  const int b = blockIdx.y, t0 = blockIdx.x*8;
  const int j = threadIdx.x, lane = j & 63, w = j >> 6;
  for (int idx = j; idx < 5120; idx += 256) {
    const int k = idx / 80, d = idx % 80;
    sf1T[idx] = a.f1w[(size_t)d*64 + k];
  }
  for (int idx = j; idx < 5120; idx += 256) {
    const int kh = idx >> 6, o = idx & 63;
    sclT[idx] = a.clw[(size_t)o*80 + kh];
  }
  __syncthreads();
  for (int ti = 0; ti < 2; ++ti) {
    const int t = t0 + w*2 + ti;
    const float* fp = (const float*)(a.fbase + ((size_t)b*T_ + t)*512);
    sfv[w][lane] = fp[lane];
    __syncthreads();
    float h1a = a.f1b[lane];
    float h1b = (lane < 16) ? a.f1b[64 + lane] : 0.f;
    for (int k = 0; k < 64; ++k) {
      const float fv = sfv[w][k];
      h1a += sf1T[k*80 + lane]*fv;
      if (lane < 16) h1b += sf1T[k*80 + 64 + lane]*fv;
    }
    sh1[w][lane] = fmaxf(h1a, 0.f);
    if (lane < 16) sh1[w][64 + lane] = fmaxf(h1b, 0.f);
    __syncthreads();
    float o = a.clb[lane];
    for (int kh = 0; kh < H1_; ++kh)
      o += sclT[kh*64 + lane]*sh1[w][kh];
    a.out[((size_t)b*T_ + t)*DOUT_ + lane] = o;
    __syncthreads();
  }
}

// ------------------------- host launcher ------------------------------------

extern "C" void kernel_launch(void* const* d_in, const int* in_sizes, int n_in,
                              void* d_out, int out_size, void* d_ws, size_t ws_size,
                              hipStream_t stream) {
  const float* x      = (const float*)d_in[0];
  const float* eps_g0 = (const float*)d_in[1];
  const float* eps_u  = (const float*)d_in[2];
  const float* egf_wih = (const float*)d_in[3],  *egf_whh = (const float*)d_in[4];
  const float* egf_bih = (const float*)d_in[5],  *egf_bhh = (const float*)d_in[6];
  const float* egb_wih = (const float*)d_in[7],  *egb_whh = (const float*)d_in[8];
  const float* egb_bih = (const float*)d_in[9],  *egb_bhh = (const float*)d_in[10];
  const float* ecf_wih = (const float*)d_in[11], *ecf_whh = (const float*)d_in[12];
  const float* ecf_bih = (const float*)d_in[13], *ecf_bhh = (const float*)d_in[14];
  const float* ecb_wih = (const float*)d_in[15], *ecb_whh = (const float*)d_in[16];
  const float* ecb_bih = (const float*)d_in[17], *ecb_bhh = (const float*)d_in[18];
  const float* con_wih = (const float*)d_in[19], *con_whh = (const float*)d_in[20];
  const float* con_bih = (const float*)d_in[21], *con_bhh = (const float*)d_in[22];
  const float* gen_wih = (const float*)d_in[23], *gen_whh = (const float*)d_in[24];
  const float* gen_bih = (const float*)d_in[25], *gen_bhh = (const float*)d_in[26];
  const float* g0m_w = (const float*)d_in[27], *g0m_b = (const float*)d_in[28];
  const float* g0v_w = (const float*)d_in[29], *g0v_b = (const float*)d_in[30];
  const float* um_w = (const float*)d_in[31], *um_b = (const float*)d_in[32];
  const float* uv_w = (const float*)d_in[33], *uv_b = (const float*)d_in[34];
  const float* fac_w = (const float*)d_in[35], *fac_b = (const float*)d_in[36];
  const float* f1_w = (const float*)d_in[37], *f1_b = (const float*)d_in[38];
  const float* cl_w = (const float*)d_in[39], *cl_b = (const float*)d_in[40];
  float* out = (float*)d_out;
  (void)ws_size; (void)in_sizes; (void)n_in; (void)out_size;

  // Workspace layout (160,407,552 B <= 167,297,024):
  //   efS  [B][T][256] f16    65,536,000  (prefix aliased by f32 f[64])
  //   ebS                     65,536,000
  //   ge   [B][TC][768] f16   25,165,824
  //   wenc [4][245760] f16     1,966,080
  //   wg6  [393216] f16          786,432
  //   w3   [49152]  f16           98,304
  //   w2   [393216] f16          786,432
  //   hgF/hgB f32                262,144
  //   S    [B][512] f32          262,144
  //   bias8 [256][8] f32           8,192
  char* ws = (char*)d_ws;
  f16* efS   = (f16*)(ws + 0);
  f16* ebS   = (f16*)(ws + 65536000ul);
  f16* geb   = (f16*)(ws + 131072000ul);
  f16* wenc  = (f16*)(ws + 156237824ul);
  f16* wg6   = (f16*)(ws + 158203904ul);
  f16* w3    = (f16*)(ws + 158990336ul);
  f16* w2    = (f16*)(ws + 159088640ul);
  float* hgF = (float*)(ws + 159875072ul);
  float* hgB = (float*)(ws + 160006144ul);
  float* S   = (float*)(ws + 160137216ul);
  float* bias8 = (float*)(ws + 160399360ul);

  PEncArgs pe;
  pe.wih[0] = egf_wih; pe.whh[0] = egf_whh;
  pe.wih[1] = ecf_wih; pe.whh[1] = ecf_whh;
  pe.wih[2] = egb_wih; pe.whh[2] = egb_whh;
  pe.wih[3] = ecb_wih; pe.whh[3] = ecb_whh;
  pe.dst = wenc;
  k_prep_enc<<<dim3(960, 4), 256, 0, stream>>>(pe);
  k_prep_gen<<<1536, 256, 0, stream>>>(con_whh, gen_whh, wg6);
  k_prep_w3<<<192, 256, 0, stream>>>(con_wih, w3);
  k_prep_w2<<<1536, 256, 0, stream>>>(con_wih, w2);
  k_prep_bias<<<1, 256, 0, stream>>>(con_bih, con_bhh, gen_bih, gen_bhh, bias8);

  EncArgs ea;
  ea.x = x;
  ea.bih[0] = egf_bih; ea.bhh[0] = egf_bhh;
  ea.bih[1] = ecf_bih; ea.bhh[1] = ecf_bhh;
  ea.bih[2] = egb_bih; ea.bhh[2] = egb_bhh;
  ea.bih[3] = ecb_bih; ea.bhh[3] = ecb_bhh;
  ea.wenc = wenc; ea.efS = efS; ea.ebS = ebS; ea.hgF = hgF; ea.hgB = hgB;
  k_encoder<<<256, 1024, 0, stream>>>(ea);

  k_g0<<<128, 256, 0, stream>>>(hgF, hgB, g0m_w, g0m_b, g0v_w, g0v_b, eps_g0, S);

  for (int c = 0; c < NCHUNK_; ++c) {
    GeArgs ga; ga.efS = efS; ga.ebS = ebS; ga.w2 = w2; ga.ge = geb; ga.t0 = c*TC_;
    k_ge<<<dim3(16, B_), 256, 0, stream>>>(ga);
    GenArgs gn;
    gn.wg6 = wg6; gn.w3 = w3; gn.ge = geb; gn.bias8 = bias8; gn.genwih = gen_wih;
    gn.umw = um_w; gn.umb = um_b; gn.uvw = uv_w; gn.uvb = uv_b;
    gn.epsu = eps_u; gn.facw = fac_w; gn.facb = fac_b;
    gn.S = S; gn.fout = (char*)ws;
    gn.t0 = c*TC_;
    gn.tcnt = (T_ - c*TC_ < TC_) ? (T_ - c*TC_) : TC_;
    k_gen<<<128, 1024, 0, stream>>>(gn);
  }

  MlpArgs ma; ma.fbase = (const char*)ws; ma.f1w = f1_w; ma.f1b = f1_b;
  ma.clw = cl_w; ma.clb = cl_b; ma.out = out;
  k_mlp<<<dim3(125, B_), 256, 0, stream>>>(ma);
}